// Round 15
// baseline (116.127 us; speedup 1.0000x reference)
//
#include <hip/hip_runtime.h>
#include <hip/hip_bf16.h>

#define N 8192        // n_users == n_recipes (required by reference broadcasting)
#define D 64
#define B_PAIRS 65536
#define FILL 0.1f
#define LOG2E 1.4426950408889634f
#define LN2 0.6931471805599453

typedef __attribute__((ext_vector_type(8))) short short8v;   // 8 bf16 in 4 VGPRs
typedef __attribute__((ext_vector_type(4))) float f32x4;

__device__ __forceinline__ float wave_reduce_sum(float v) {
  #pragma unroll
  for (int m = 1; m < 64; m <<= 1) v += __shfl_xor(v, m, 64);
  return v;
}

__device__ __forceinline__ float bf16_to_f32(unsigned short u) {
  unsigned int b = ((unsigned int)u) << 16;
  return __builtin_bit_cast(float, b);
}

// v_exp_f32 via builtin (compiler handles the trans-op wait states; raw asm
// without s_nop corrupted results in R8). Args bounded: |x| <= ~1.45.
__device__ __forceinline__ float fast_exp2(float x) {
#if __has_builtin(__builtin_amdgcn_exp2f)
  return __builtin_amdgcn_exp2f(x);
#else
  float r;
  asm("v_exp_f32 %0, %1\n\ts_nop 1" : "=v"(r) : "v"(x));
  return r;
#endif
}

// one wave per row: L2-normalize, emit bf16 row (RNE). U side pre-scaled by
// log2(e) so the gemm uses raw exp2 (corrected by *ln2 on cos-sum terms).
// Side duty: zero-init accumulators + completion counter (graph-replay-safe).
__global__ __launch_bounds__(256) void norm_kernel(const float* __restrict__ U,
                                                   const float* __restrict__ R,
                                                   short* __restrict__ Ub,
                                                   short* __restrict__ Rb,
                                                   float* __restrict__ rowRMe,
                                                   float* __restrict__ sumU,
                                                   float* __restrict__ sumR,
                                                   double* __restrict__ scal) {
  const int t = threadIdx.x;
  if (blockIdx.x < 32) {
    rowRMe[blockIdx.x * 256 + t] = 0.f;
  } else if (blockIdx.x == 32) {
    if (t < 64) sumU[t] = 0.f;
    else if (t < 128) sumR[t - 64] = 0.f;
    else if (t < 136) scal[t - 128] = 0.0;   // scal[0..7]; [7] doubles as counter
  }
  int row = blockIdx.x * 4 + (t >> 6);
  int lane = t & 63;
  bool isU = row < N;
  const float* src = isU ? (U + (size_t)row * D) : (R + (size_t)(row - N) * D);
  short* dst = isU ? (Ub + (size_t)row * D) : (Rb + (size_t)(row - N) * D);
  float v = src[lane];
  float s = wave_reduce_sum(v * v);
  float nv = v * rsqrtf(s) * (isU ? LOG2E : 1.0f);   // norms ~8; eps never binds
  unsigned int bits = __builtin_bit_cast(unsigned int, nv);
  unsigned int r = (bits + 0x7FFFu + ((bits >> 16) & 1u)) >> 16;   // RNE to bf16
  dst[lane] = (short)r;
}

// Fused 1024-thread (16-wave) kernel. Rationale: occupancy has been stuck at
// ~2.5 BLOCKS/CU in every round regardless of VGPR/LDS; with 16-wave blocks
// that same cap is 32+ waves/CU = full wave occupancy, finally hiding the
// load->MFMA->exp dependency chains (the ~75% stall R6-R14 never moved).
// blocks 0..1023:   gemm — wave w owns tile bid*16+w (16384 64x64 tiles),
//                   barrier-free, straight-line, fused exp + reductions,
//                   disjoint partial stores. Identical math to R12.
// blocks 1024..1087: scattered interactions, 8 lanes/pair, 1024 pairs/block,
//                   per-block combine -> ONE double atomic per scalar/block.
//                   Dedup ignored (~32 collisions, ~1e-3 each).
// blocks 1088..1103: column sums of Ub/Rb for S_cos.
__global__ __launch_bounds__(1024, 8) void mega_kernel(
    const short* __restrict__ Ub, const short* __restrict__ Rb,
    const float* __restrict__ ratings, const float* __restrict__ cossim,
    const int* __restrict__ u_idx, const int* __restrict__ i_idx,
    float* __restrict__ rowRMe, float* __restrict__ sumU,
    float* __restrict__ sumR, double* __restrict__ scal,
    float* __restrict__ rowpart, float* __restrict__ colpart) {
  __shared__ float sm[1024];
  __shared__ float sm2[16];
  const int bid = blockIdx.x;
  const int t = threadIdx.x;
  const int wid = t >> 6, lane = t & 63;

  if (bid < 1024) {
    const int g = bid * 16 + wid;              // tile id 0..16383
    const int cx = g & 127, by = g >> 7;       // 128 x 128 tiles of 64x64
    const int rowbase = by * 64;
    const int colbase = cx * 64;
    const int lrow = lane & 15;   // fragment row (A) / col (B) index
    const int kgrp = lane >> 4;   // k-group: k = ks*32 + kgrp*8 + j

    short8v aF[4][2], bF[4][2];
    #pragma unroll
    for (int m = 0; m < 4; ++m) {
      const short* arow = Ub + (size_t)(rowbase + m * 16 + lrow) * D + kgrp * 8;
      aF[m][0] = *reinterpret_cast<const short8v*>(arow);
      aF[m][1] = *reinterpret_cast<const short8v*>(arow + 32);
    }
    #pragma unroll
    for (int n = 0; n < 4; ++n) {
      const short* brow = Rb + (size_t)(colbase + n * 16 + lrow) * D + kgrp * 8;
      bF[n][0] = *reinterpret_cast<const short8v*>(brow);
      bF[n][1] = *reinterpret_cast<const short8v*>(brow + 32);
    }

    float rowacc[4][4] = {};   // [m][reg]
    float colaccR[4];
    #pragma unroll
    for (int n = 0; n < 4; ++n) {
      f32x4 acc[4] = {};
      #pragma unroll
      for (int m = 0; m < 4; ++m)
        acc[m] = __builtin_amdgcn_mfma_f32_16x16x32_bf16(aF[m][0], bF[n][0], acc[m], 0, 0, 0);
      #pragma unroll
      for (int m = 0; m < 4; ++m)
        acc[m] = __builtin_amdgcn_mfma_f32_16x16x32_bf16(aF[m][1], bF[n][1], acc[m], 0, 0, 0);
      float p0 = 0.f, p1 = 0.f, p2 = 0.f, p3 = 0.f;
      #pragma unroll
      for (int r = 0; r < 4; ++r) {
        float e0 = fast_exp2(acc[0][r]); rowacc[0][r] += e0; p0 += e0;
        float e1 = fast_exp2(acc[1][r]); rowacc[1][r] += e1; p1 += e1;
        float e2 = fast_exp2(acc[2][r]); rowacc[2][r] += e2; p2 += e2;
        float e3 = fast_exp2(acc[3][r]); rowacc[3][r] += e3; p3 += e3;
      }
      float cacc = (p0 + p1) + (p2 + p3);
      cacc += __shfl_xor(cacc, 16, 64);
      cacc += __shfl_xor(cacc, 32, 64);
      colaccR[n] = cacc;                       // valid in lanes<16
    }

    // row sums: reduce over the 16 col-lanes; lanes lrow==0 write 16 rows each
    #pragma unroll
    for (int m = 0; m < 4; ++m)
      #pragma unroll
      for (int r = 0; r < 4; ++r) {
        float v = rowacc[m][r];
        v += __shfl_xor(v, 1, 64);
        v += __shfl_xor(v, 2, 64);
        v += __shfl_xor(v, 4, 64);
        v += __shfl_xor(v, 8, 64);
        if (lrow == 0)
          rowpart[(size_t)cx * N + rowbase + m * 16 + kgrp * 4 + r] = v;
      }
    // col sums: lanes 0..15 write 16 consecutive floats per n (coalesced 64B)
    if (lane < 16)
      #pragma unroll
      for (int n = 0; n < 4; ++n)
        colpart[(size_t)by * N + colbase + n * 16 + lrow] = colaccR[n];

  } else if (bid < 1088) {
    const int sb = bid - 1024;                 // 0..63, 1024 pairs each
    const int grp = lane >> 3, sub = lane & 7;
    float exacc = 0.f, msacc = 0.f;
    #pragma unroll 2
    for (int pass = 0; pass < 8; ++pass) {
      const int p = sb * 1024 + pass * 128 + wid * 8 + grp;   // pair id
      int u = u_idx[p], i = i_idx[p];
      short8v uv = *reinterpret_cast<const short8v*>(Ub + (size_t)u * D + sub * 8);
      short8v iv = *reinterpret_cast<const short8v*>(Rb + (size_t)i * D + sub * 8);
      float pd = 0.f;
      #pragma unroll
      for (int e = 0; e < 8; ++e)
        pd += bf16_to_f32((unsigned short)uv[e]) * bf16_to_f32((unsigned short)iv[e]);
      pd += __shfl_xor(pd, 1, 64);
      pd += __shfl_xor(pd, 2, 64);
      pd += __shfl_xor(pd, 4, 64);             // dot complete in all 8 lanes
      if (sub == 0) {
        float rv = ratings[p];
        exacc += (rv - FILL) * pd;             // scaled by log2e; fixed later
        float dd = rv - cossim[p];
        msacc += dd * dd;
        atomicAdd(&rowRMe[u], rv - FILL);      // spread over 8192 addresses
      }
    }
    exacc += __shfl_xor(exacc, 8, 64);
    exacc += __shfl_xor(exacc, 16, 64);
    exacc += __shfl_xor(exacc, 32, 64);
    msacc += __shfl_xor(msacc, 8, 64);
    msacc += __shfl_xor(msacc, 16, 64);
    msacc += __shfl_xor(msacc, 32, 64);
    if (lane == 0) { sm[wid] = exacc; sm2[wid] = msacc; }
    __syncthreads();
    if (t == 0) {
      float s = 0.f;
      #pragma unroll
      for (int w = 0; w < 16; ++w) s += sm[w];
      atomicAdd(&scal[1], (double)s);
    } else if (t == 64) {
      float s = 0.f;
      #pragma unroll
      for (int w = 0; w < 16; ++w) s += sm2[w];
      atomicAdd(&scal[2], (double)s);
    }

  } else {
    // column sums: 16 blocks, each 1024 rows of one matrix. lane l reads row
    // (base + l>>3), cols (l&7)*8..+7 as one short8v; 8 passes of 128 rows.
    int sb = bid - 1088;                   // 0..15
    const short* M = (sb < 8) ? Ub : Rb;
    float* dst = (sb < 8) ? sumU : sumR;
    int rbase = (sb & 7) * 1024;
    float pc[8] = {};
    #pragma unroll
    for (int p = 0; p < 8; ++p) {
      int row = rbase + p * 128 + wid * 8 + (lane >> 3);
      short8v v = *reinterpret_cast<const short8v*>(M + (size_t)row * D + (lane & 7) * 8);
      #pragma unroll
      for (int e = 0; e < 8; ++e)
        pc[e] += bf16_to_f32((unsigned short)v[e]);
    }
    #pragma unroll
    for (int e = 0; e < 8; ++e) {
      pc[e] += __shfl_xor(pc[e], 8, 64);
      pc[e] += __shfl_xor(pc[e], 16, 64);
      pc[e] += __shfl_xor(pc[e], 32, 64);
    }
    if (lane < 8)
      #pragma unroll
      for (int e = 0; e < 8; ++e) sm[wid * 64 + lane * 8 + e] = pc[e];
    __syncthreads();
    if (t < 64) {
      float s = 0.f;
      #pragma unroll
      for (int w = 0; w < 16; ++w) s += sm[w * 64 + t];
      atomicAdd(&dst[t], s);
    }
  }
}

// 128 blocks x 64 rows; 4 thread-quarters per row reduce 32 slices each of
// rowpart/colpart, LDS-combine, log term -> scal[3]. Last block (completion
// counter in scal[7]) computes the final scalar output.
__global__ __launch_bounds__(256) void final_out_kernel(
    const float* __restrict__ rowpart, const float* __restrict__ colpart,
    const float* __restrict__ rowRMe, const float* __restrict__ sumU,
    const float* __restrict__ sumR, double* __restrict__ scal,
    float* __restrict__ out) {
  __shared__ float smr[256];
  __shared__ float smc[256];
  __shared__ unsigned int done;
  const int t = threadIdx.x;
  const int q = t >> 6, r = t & 63;          // quarter, row-in-block
  const int i = blockIdx.x * 64 + r;
  float rsum = 0.f, csum = 0.f;
  #pragma unroll 8
  for (int p = q * 32; p < q * 32 + 32; ++p) {
    rsum += rowpart[(size_t)p * N + i];
    csum += colpart[(size_t)p * N + i];
  }
  smr[t] = rsum; smc[t] = csum;
  __syncthreads();
  if (t < 64) {
    rsum = smr[t] + smr[64 + t] + smr[128 + t] + smr[192 + t];
    csum = smc[t] + smc[64 + t] + smc[128 + t] + smc[192 + t];
    float term = (FILL * (float)N + rowRMe[i]) * 0.5f * (logf(rsum) + logf(csum));
    float s = wave_reduce_sum(term);
    if (t == 0) {
      atomicAdd(&scal[3], (double)s);
      __threadfence();
    }
  }
  __syncthreads();
  unsigned int* cnt = (unsigned int*)(scal + 7);
  if (t == 0) {
    __threadfence();
    done = atomicAdd(cnt, 1u);
  }
  __syncthreads();
  if (done == 127 && t < 64) {               // last of 128 blocks finishes up
    __threadfence();
    float p = sumU[t] * sumR[t];
    p = wave_reduce_sum(p);                  // = log2e * sum(cos)
    if (t == 0) {
      double T = (0.1 * (double)p + scal[1]) * LN2;   // undo log2e scaling
      double contrastive = (scal[3] - T) / (double)N;
      double mse = scal[2] / (double)B_PAIRS;
      out[0] = (float)(0.5 * contrastive + 0.5 * mse);
      *cnt = 0u;                             // leave counter clean for replay
    }
  }
}

extern "C" void kernel_launch(void* const* d_in, const int* in_sizes, int n_in,
                              void* d_out, int out_size, void* d_ws, size_t ws_size,
                              hipStream_t stream) {
  const float* U       = (const float*)d_in[0];
  const float* R       = (const float*)d_in[1];
  const float* ratings = (const float*)d_in[2];
  const float* cossim  = (const float*)d_in[3];
  const int*   u_idx   = (const int*)d_in[4];
  const int*   i_idx   = (const int*)d_in[5];

  float* ws      = (float*)d_ws;
  float* rowRMe  = ws;                      // [8192]
  float* sumU    = ws + 8192;               // [64]
  float* sumR    = ws + 8256;               // [64]
  double* scal   = (double*)(ws + 8320);    // 8 doubles; [7] = completion counter
  short* Ub      = (short*)(ws + 8448);     // [N*D] bf16 (scaled by log2e)
  short* Rb      = Ub + (size_t)N * D;      // [N*D] bf16
  float* rowpart = ws + 532736;             // [128][8192] per col-tile cx
  float* colpart = ws + 1581312;            // [128][8192] per row-tile by
  // total ws use: 2629888 floats ≈ 10.5 MB

  norm_kernel<<<(2 * N) / 4, 256, 0, stream>>>(U, R, Ub, Rb, rowRMe, sumU, sumR, scal);

  mega_kernel<<<1104, 1024, 0, stream>>>(Ub, Rb, ratings, cossim, u_idx, i_idx,
                                         rowRMe, sumU, sumR, scal, rowpart, colpart);

  final_out_kernel<<<128, 256, 0, stream>>>(rowpart, colpart, rowRMe,
                                            sumU, sumR, scal, (float*)d_out);
}

// Round 16
// 92.559 us; speedup vs baseline: 1.2546x; 1.2546x over previous
//
#include <hip/hip_runtime.h>
#include <hip/hip_bf16.h>

#define N 8192        // n_users == n_recipes (required by reference broadcasting)
#define D 64
#define B_PAIRS 65536
#define FILL 0.1f
#define LOG2E 1.4426950408889634f
#define LN2 0.6931471805599453

typedef __attribute__((ext_vector_type(8))) short short8v;   // 8 bf16 in 4 VGPRs
typedef __attribute__((ext_vector_type(4))) float f32x4;

__device__ __forceinline__ float wave_reduce_sum(float v) {
  #pragma unroll
  for (int m = 1; m < 64; m <<= 1) v += __shfl_xor(v, m, 64);
  return v;
}

__device__ __forceinline__ float bf16_to_f32(unsigned short u) {
  unsigned int b = ((unsigned int)u) << 16;
  return __builtin_bit_cast(float, b);
}

// v_exp_f32 via builtin (compiler handles the trans-op wait states; raw asm
// without s_nop corrupted results in R8). Args bounded: |x| <= ~1.45.
__device__ __forceinline__ float fast_exp2(float x) {
#if __has_builtin(__builtin_amdgcn_exp2f)
  return __builtin_amdgcn_exp2f(x);
#else
  float r;
  asm("v_exp_f32 %0, %1\n\ts_nop 1" : "=v"(r) : "v"(x));
  return r;
#endif
}

// one wave per row: L2-normalize, emit bf16 row (RNE). U side pre-scaled by
// log2(e) so the gemm uses raw exp2 (corrected by *ln2 on cos-sum terms).
// Side duty: zero-init accumulators + completion counter (graph-replay-safe).
__global__ __launch_bounds__(256) void norm_kernel(const float* __restrict__ U,
                                                   const float* __restrict__ R,
                                                   short* __restrict__ Ub,
                                                   short* __restrict__ Rb,
                                                   float* __restrict__ rowRMe,
                                                   float* __restrict__ sumU,
                                                   float* __restrict__ sumR,
                                                   double* __restrict__ scal) {
  const int t = threadIdx.x;
  if (blockIdx.x < 32) {
    rowRMe[blockIdx.x * 256 + t] = 0.f;
  } else if (blockIdx.x == 32) {
    if (t < 64) sumU[t] = 0.f;
    else if (t < 128) sumR[t - 64] = 0.f;
    else if (t < 136) scal[t - 128] = 0.0;   // scal[0..7]; [7] doubles as counter
  }
  int row = blockIdx.x * 4 + (t >> 6);
  int lane = t & 63;
  bool isU = row < N;
  const float* src = isU ? (U + (size_t)row * D) : (R + (size_t)(row - N) * D);
  short* dst = isU ? (Ub + (size_t)row * D) : (Rb + (size_t)(row - N) * D);
  float v = src[lane];
  float s = wave_reduce_sum(v * v);
  float nv = v * rsqrtf(s) * (isU ? LOG2E : 1.0f);   // norms ~8; eps never binds
  unsigned int bits = __builtin_bit_cast(unsigned int, nv);
  unsigned int r = (bits + 0x7FFFu + ((bits >> 16) & 1u)) >> 16;   // RNE to bf16
  dst[lane] = (short)r;
}

// Fused kernel, 256-thread blocks, LOW-REGISTER gemm waves.
// Occupancy steps on gfx950 are 8/4/2 waves per SIMD at <=64/<=128/<=256
// unified VGPRs. The old 64x64 wave tile needed ~110 (aF32+bF32+acc16+row16)
// -> 4 waves/SIMD forever (the R6-R14 ~45us plateau: dependency stalls with
// too few waves to hide them). A 16x256 wave tile needs aF8+bF8+acc4+row4
// ~45 regs -> 8 waves/SIMD. R15 proved occupancy moves (70%) when residency
// allows; this fits the budget WITHOUT spilling (R15's (1024,8) forced
// VGPR=32 -> 286MB scratch).
// blocks 0..4095:    gemm. Block = 64 rows x 256 cols (4 waves stacked by
//                    row); wave = 16 rows x 256 cols, 16 n-steps x 2 MFMA.
//                    Col partials in block LDS; row partials shuffle-reduced.
// blocks 4096..4351: scattered interactions (R11-verified form).
// blocks 4352..4415: column sums of Ub/Rb for S_cos (R11-verified form).
__global__ __launch_bounds__(256, 8) void mega_kernel(
    const short* __restrict__ Ub, const short* __restrict__ Rb,
    const float* __restrict__ ratings, const float* __restrict__ cossim,
    const int* __restrict__ u_idx, const int* __restrict__ i_idx,
    float* __restrict__ rowRMe, float* __restrict__ sumU,
    float* __restrict__ sumR, double* __restrict__ scal,
    float* __restrict__ rowpart, float* __restrict__ colpart) {
  __shared__ float cs[256];      // gemm: col partials | aux/colsum: scratch
  __shared__ float rs_lds[64];   // gemm: row partials | aux: wave partials
  const int bid = blockIdx.x;
  const int t = threadIdx.x;
  const int wid = t >> 6, lane = t & 63;

  if (bid < 4096) {
    const int rsb = bid >> 5;                  // row super-block 0..127
    const int tx = bid & 31;                   // col chunk 0..31
    const int rowbase = rsb * 64 + wid * 16;   // wave's 16 rows
    const int colbase = tx * 256;              // block's 256 cols
    const int lrow = lane & 15;   // fragment row (A) / col (B) index
    const int kgrp = lane >> 4;   // k-group: k = ks*32 + kgrp*8 + j

    cs[t] = 0.f;

    const short* arow = Ub + (size_t)(rowbase + lrow) * D + kgrp * 8;
    short8v aF0 = *reinterpret_cast<const short8v*>(arow);
    short8v aF1 = *reinterpret_cast<const short8v*>(arow + 32);
    const short* bbase = Rb + (size_t)(colbase + lrow) * D + kgrp * 8;

    float rowacc[4] = {0.f, 0.f, 0.f, 0.f};
    __syncthreads();             // cs init complete

    #pragma unroll 4
    for (int n = 0; n < 16; ++n) {
      const short* brow = bbase + (size_t)n * (16 * D);
      short8v b0 = *reinterpret_cast<const short8v*>(brow);
      short8v b1 = *reinterpret_cast<const short8v*>(brow + 32);
      f32x4 acc = {};
      acc = __builtin_amdgcn_mfma_f32_16x16x32_bf16(aF0, b0, acc, 0, 0, 0);
      acc = __builtin_amdgcn_mfma_f32_16x16x32_bf16(aF1, b1, acc, 0, 0, 0);
      float e0 = fast_exp2(acc[0]);
      float e1 = fast_exp2(acc[1]);
      float e2 = fast_exp2(acc[2]);
      float e3 = fast_exp2(acc[3]);
      rowacc[0] += e0; rowacc[1] += e1; rowacc[2] += e2; rowacc[3] += e3;
      float cacc = (e0 + e1) + (e2 + e3);
      cacc += __shfl_xor(cacc, 16, 64);
      cacc += __shfl_xor(cacc, 32, 64);
      if (lane < 16) atomicAdd(&cs[n * 16 + lrow], cacc);   // LDS, block scope
    }

    // row sums: reduce over the 16 col-lanes; unique writer per row
    #pragma unroll
    for (int r = 0; r < 4; ++r) {
      float v = rowacc[r];
      v += __shfl_xor(v, 1, 64);
      v += __shfl_xor(v, 2, 64);
      v += __shfl_xor(v, 4, 64);
      v += __shfl_xor(v, 8, 64);
      if (lrow == 0) rs_lds[wid * 16 + kgrp * 4 + r] = v;
    }
    __syncthreads();

    if (t < 64)
      rowpart[(size_t)tx * N + rsb * 64 + t] = rs_lds[t];
    colpart[(size_t)rsb * N + colbase + t] = cs[t];

  } else if (bid < 4352) {
    const int sb = bid - 4096;                 // 0..255, 256 pairs each
    const int grp = lane >> 3, sub = lane & 7;
    float exacc = 0.f, msacc = 0.f;
    #pragma unroll 2
    for (int pass = 0; pass < 8; ++pass) {
      const int p = sb * 256 + pass * 32 + wid * 8 + grp;   // pair id
      int u = u_idx[p], i = i_idx[p];
      short8v uv = *reinterpret_cast<const short8v*>(Ub + (size_t)u * D + sub * 8);
      short8v iv = *reinterpret_cast<const short8v*>(Rb + (size_t)i * D + sub * 8);
      float pd = 0.f;
      #pragma unroll
      for (int e = 0; e < 8; ++e)
        pd += bf16_to_f32((unsigned short)uv[e]) * bf16_to_f32((unsigned short)iv[e]);
      pd += __shfl_xor(pd, 1, 64);
      pd += __shfl_xor(pd, 2, 64);
      pd += __shfl_xor(pd, 4, 64);             // dot complete in all 8 lanes
      if (sub == 0) {
        float rv = ratings[p];
        exacc += (rv - FILL) * pd;             // scaled by log2e; fixed later
        float dd = rv - cossim[p];
        msacc += dd * dd;
        atomicAdd(&rowRMe[u], rv - FILL);      // spread over 8192 addresses
      }
    }
    exacc += __shfl_xor(exacc, 8, 64);
    exacc += __shfl_xor(exacc, 16, 64);
    exacc += __shfl_xor(exacc, 32, 64);
    msacc += __shfl_xor(msacc, 8, 64);
    msacc += __shfl_xor(msacc, 16, 64);
    msacc += __shfl_xor(msacc, 32, 64);
    if (lane == 0) { rs_lds[wid] = exacc; rs_lds[8 + wid] = msacc; }
    __syncthreads();
    if (t == 0)
      atomicAdd(&scal[1], (double)(rs_lds[0] + rs_lds[1] + rs_lds[2] + rs_lds[3]));
    else if (t == 64)
      atomicAdd(&scal[2], (double)(rs_lds[8] + rs_lds[9] + rs_lds[10] + rs_lds[11]));

  } else {
    // column sums. lane l reads row (base + l>>3), cols (l&7)*8..+7 as one
    // short8v; 8 passes of 32 rows per block.
    int sb = bid - 4352;                   // 0..63
    const short* M = (sb < 32) ? Ub : Rb;
    float* dst = (sb < 32) ? sumU : sumR;
    int rbase = (sb & 31) * 256;
    float pc[8] = {};
    #pragma unroll
    for (int p = 0; p < 8; ++p) {
      int row = rbase + p * 32 + wid * 8 + (lane >> 3);
      short8v v = *reinterpret_cast<const short8v*>(M + (size_t)row * D + (lane & 7) * 8);
      #pragma unroll
      for (int e = 0; e < 8; ++e)
        pc[e] += bf16_to_f32((unsigned short)v[e]);
    }
    #pragma unroll
    for (int e = 0; e < 8; ++e) {
      pc[e] += __shfl_xor(pc[e], 8, 64);
      pc[e] += __shfl_xor(pc[e], 16, 64);
      pc[e] += __shfl_xor(pc[e], 32, 64);
    }
    if (lane < 8)
      #pragma unroll
      for (int e = 0; e < 8; ++e) cs[wid * 64 + lane * 8 + e] = pc[e];
    __syncthreads();
    if (t < 64)
      atomicAdd(&dst[t], cs[t] + cs[64 + t] + cs[128 + t] + cs[192 + t]);
  }
}

// 128 blocks x 64 rows; 4 thread-quarters per row reduce 8 row-slices +
// 32 col-slices each, LDS-combine, log term -> scal[3]. Last block
// (completion counter in scal[7]) computes the final scalar output.
__global__ __launch_bounds__(256) void final_out_kernel(
    const float* __restrict__ rowpart, const float* __restrict__ colpart,
    const float* __restrict__ rowRMe, const float* __restrict__ sumU,
    const float* __restrict__ sumR, double* __restrict__ scal,
    float* __restrict__ out) {
  __shared__ float smr[256];
  __shared__ float smc[256];
  __shared__ unsigned int done;
  const int t = threadIdx.x;
  const int q = t >> 6, r = t & 63;          // quarter, row-in-block
  const int i = blockIdx.x * 64 + r;
  float rsum = 0.f, csum = 0.f;
  #pragma unroll 8
  for (int p = q * 8; p < q * 8 + 8; ++p) rsum += rowpart[(size_t)p * N + i];
  #pragma unroll 8
  for (int p = q * 32; p < q * 32 + 32; ++p) csum += colpart[(size_t)p * N + i];
  smr[t] = rsum; smc[t] = csum;
  __syncthreads();
  if (t < 64) {
    rsum = smr[t] + smr[64 + t] + smr[128 + t] + smr[192 + t];
    csum = smc[t] + smc[64 + t] + smc[128 + t] + smc[192 + t];
    float term = (FILL * (float)N + rowRMe[i]) * 0.5f * (logf(rsum) + logf(csum));
    float s = wave_reduce_sum(term);
    if (t == 0) {
      atomicAdd(&scal[3], (double)s);
      __threadfence();
    }
  }
  __syncthreads();
  unsigned int* cnt = (unsigned int*)(scal + 7);
  if (t == 0) {
    __threadfence();
    done = atomicAdd(cnt, 1u);
  }
  __syncthreads();
  if (done == 127 && t < 64) {               // last of 128 blocks finishes up
    __threadfence();
    float p = sumU[t] * sumR[t];
    p = wave_reduce_sum(p);                  // = log2e * sum(cos)
    if (t == 0) {
      double T = (0.1 * (double)p + scal[1]) * LN2;   // undo log2e scaling
      double contrastive = (scal[3] - T) / (double)N;
      double mse = scal[2] / (double)B_PAIRS;
      out[0] = (float)(0.5 * contrastive + 0.5 * mse);
      *cnt = 0u;                             // leave counter clean for replay
    }
  }
}

extern "C" void kernel_launch(void* const* d_in, const int* in_sizes, int n_in,
                              void* d_out, int out_size, void* d_ws, size_t ws_size,
                              hipStream_t stream) {
  const float* U       = (const float*)d_in[0];
  const float* R       = (const float*)d_in[1];
  const float* ratings = (const float*)d_in[2];
  const float* cossim  = (const float*)d_in[3];
  const int*   u_idx   = (const int*)d_in[4];
  const int*   i_idx   = (const int*)d_in[5];

  float* ws      = (float*)d_ws;
  float* rowRMe  = ws;                      // [8192]
  float* sumU    = ws + 8192;               // [64]
  float* sumR    = ws + 8256;               // [64]
  double* scal   = (double*)(ws + 8320);    // 8 doubles; [7] = completion counter
  short* Ub      = (short*)(ws + 8448);     // [N*D] bf16 (scaled by log2e)
  short* Rb      = Ub + (size_t)N * D;      // [N*D] bf16
  float* rowpart = ws + 532736;             // [32][8192]  slice per col-chunk tx
  float* colpart = ws + 794880;             // [128][8192] slice per row-super rsb
  // total ws use: 1843456 floats ≈ 7.4 MB

  norm_kernel<<<(2 * N) / 4, 256, 0, stream>>>(U, R, Ub, Rb, rowRMe, sumU, sumR, scal);

  mega_kernel<<<4416, 256, 0, stream>>>(Ub, Rb, ratings, cossim, u_idx, i_idx,
                                        rowRMe, sumU, sumR, scal, rowpart, colpart);

  final_out_kernel<<<128, 256, 0, stream>>>(rowpart, colpart, rowRMe,
                                            sumU, sumR, scal, (float*)d_out);
}

// Round 17
// 62.456 us; speedup vs baseline: 1.8593x; 1.4820x over previous
//
#include <hip/hip_runtime.h>
#include <hip/hip_bf16.h>

#define N 8192        // n_users == n_recipes (required by reference broadcasting)
#define D 64
#define B_PAIRS 65536
#define FILL 0.1f
#define LOG2E 1.4426950408889634f
#define LN2 0.6931471805599453

typedef __attribute__((ext_vector_type(8))) short short8v;   // 8 bf16 in 4 VGPRs
typedef __attribute__((ext_vector_type(4))) float f32x4;

__device__ __forceinline__ float wave_reduce_sum(float v) {
  #pragma unroll
  for (int m = 1; m < 64; m <<= 1) v += __shfl_xor(v, m, 64);
  return v;
}

__device__ __forceinline__ float bf16_to_f32(unsigned short u) {
  unsigned int b = ((unsigned int)u) << 16;
  return __builtin_bit_cast(float, b);
}

// v_exp_f32 via builtin (compiler handles the trans-op wait states; raw asm
// without s_nop corrupted results in R8). Args bounded: |x| <= ~1.45.
__device__ __forceinline__ float fast_exp2(float x) {
#if __has_builtin(__builtin_amdgcn_exp2f)
  return __builtin_amdgcn_exp2f(x);
#else
  float r;
  asm("v_exp_f32 %0, %1\n\ts_nop 1" : "=v"(r) : "v"(x));
  return r;
#endif
}

// one wave per row: L2-normalize, emit bf16 row (RNE). U side pre-scaled by
// log2(e) so the gemm uses raw exp2 (corrected by *ln2 on cos-sum terms).
// Side duty: zero-init accumulators + completion counter (graph-replay-safe).
__global__ __launch_bounds__(256) void norm_kernel(const float* __restrict__ U,
                                                   const float* __restrict__ R,
                                                   short* __restrict__ Ub,
                                                   short* __restrict__ Rb,
                                                   float* __restrict__ rowRMe,
                                                   float* __restrict__ sumU,
                                                   float* __restrict__ sumR,
                                                   double* __restrict__ scal) {
  const int t = threadIdx.x;
  if (blockIdx.x < 32) {
    rowRMe[blockIdx.x * 256 + t] = 0.f;
  } else if (blockIdx.x == 32) {
    if (t < 64) sumU[t] = 0.f;
    else if (t < 128) sumR[t - 64] = 0.f;
    else if (t < 136) scal[t - 128] = 0.0;   // scal[0..7]; [7] doubles as counter
  }
  int row = blockIdx.x * 4 + (t >> 6);
  int lane = t & 63;
  bool isU = row < N;
  const float* src = isU ? (U + (size_t)row * D) : (R + (size_t)(row - N) * D);
  short* dst = isU ? (Ub + (size_t)row * D) : (Rb + (size_t)(row - N) * D);
  float v = src[lane];
  float s = wave_reduce_sum(v * v);
  float nv = v * rsqrtf(s) * (isU ? LOG2E : 1.0f);   // norms ~8; eps never binds
  unsigned int bits = __builtin_bit_cast(unsigned int, nv);
  unsigned int r = (bits + 0x7FFFu + ((bits >> 16) & 1u)) >> 16;   // RNE to bf16
  dst[lane] = (short)r;
}

// Fused kernel. Consolidation of best-measured pieces:
// blocks 0..4095:    R9's gemm VERBATIM (39.6us — best section ever measured):
//                    128x128 block, 4 waves 2x2, straight-line 16 fragment
//                    loads after the init-barrier, fused exp + reductions,
//                    LDS combine, COALESCED partial stores (R12's scattered
//                    4B stores doubled WRITE_SIZE via partial-line RMW).
// blocks 4096..4351: scattered interactions (R11-verified): 8 lanes/pair,
//                    256 pairs/block, per-block combine -> ONE double atomic
//                    per scalar/block. Dedup ignored (~32 collisions, ~1e-3).
// blocks 4352..4415: column sums of Ub/Rb for S_cos (R11-verified).
__global__ __launch_bounds__(256, 4) void mega_kernel(
    const short* __restrict__ Ub, const short* __restrict__ Rb,
    const float* __restrict__ ratings, const float* __restrict__ cossim,
    const int* __restrict__ u_idx, const int* __restrict__ i_idx,
    float* __restrict__ rowRMe, float* __restrict__ sumU,
    float* __restrict__ sumR, double* __restrict__ scal,
    float* __restrict__ rowpart, float* __restrict__ colpart) {
  __shared__ float sm[256];      // gemm: [0..127]=rs, [128..255]=cs
  const int bid = blockIdx.x;
  const int t = threadIdx.x;
  const int wid = t >> 6, lane = t & 63;

  if (bid < 4096) {
    const int cx = bid & 63, by = bid >> 6;
    const int wr = wid >> 1, wc = wid & 1;
    const int rowbase = by * 128 + wr * 64;
    const int colbase = cx * 128 + wc * 64;
    const int lrow = lane & 15;   // fragment row (A) / col (B) index
    const int kgrp = lane >> 4;   // k-group: k = ks*32 + kgrp*8 + j

    sm[t] = 0.f;
    __syncthreads();             // BEFORE loads: barrier drain can't stall prefetch

    short8v aF[4][2], bF[4][2];
    #pragma unroll
    for (int m = 0; m < 4; ++m) {
      const short* arow = Ub + (size_t)(rowbase + m * 16 + lrow) * D + kgrp * 8;
      aF[m][0] = *reinterpret_cast<const short8v*>(arow);
      aF[m][1] = *reinterpret_cast<const short8v*>(arow + 32);
    }
    #pragma unroll
    for (int n = 0; n < 4; ++n) {
      const short* brow = Rb + (size_t)(colbase + n * 16 + lrow) * D + kgrp * 8;
      bF[n][0] = *reinterpret_cast<const short8v*>(brow);
      bF[n][1] = *reinterpret_cast<const short8v*>(brow + 32);
    }

    float rowacc[4][4] = {};   // [m][reg]
    #pragma unroll
    for (int n = 0; n < 4; ++n) {
      f32x4 acc[4] = {};
      #pragma unroll
      for (int m = 0; m < 4; ++m)
        acc[m] = __builtin_amdgcn_mfma_f32_16x16x32_bf16(aF[m][0], bF[n][0], acc[m], 0, 0, 0);
      #pragma unroll
      for (int m = 0; m < 4; ++m)
        acc[m] = __builtin_amdgcn_mfma_f32_16x16x32_bf16(aF[m][1], bF[n][1], acc[m], 0, 0, 0);
      float p0 = 0.f, p1 = 0.f, p2 = 0.f, p3 = 0.f;
      #pragma unroll
      for (int r = 0; r < 4; ++r) {
        float e0 = fast_exp2(acc[0][r]); rowacc[0][r] += e0; p0 += e0;
        float e1 = fast_exp2(acc[1][r]); rowacc[1][r] += e1; p1 += e1;
        float e2 = fast_exp2(acc[2][r]); rowacc[2][r] += e2; p2 += e2;
        float e3 = fast_exp2(acc[3][r]); rowacc[3][r] += e3; p3 += e3;
      }
      float cacc = (p0 + p1) + (p2 + p3);
      cacc += __shfl_xor(cacc, 16, 64);
      cacc += __shfl_xor(cacc, 32, 64);
      if (lane < 16) atomicAdd(&sm[128 + wc * 64 + n * 16 + lrow], cacc);  // LDS
    }

    // row epilogue: reduce over lrow; writer lanes cover 16 rows via kgrp,reg
    #pragma unroll
    for (int m = 0; m < 4; ++m)
      #pragma unroll
      for (int r = 0; r < 4; ++r) {
        float v = rowacc[m][r];
        v += __shfl_xor(v, 1, 64);
        v += __shfl_xor(v, 2, 64);
        v += __shfl_xor(v, 4, 64);
        v += __shfl_xor(v, 8, 64);
        if (lrow == 0)
          atomicAdd(&sm[wr * 64 + m * 16 + kgrp * 4 + r], v);             // LDS
      }
    __syncthreads();

    // coalesced partial stores (contiguous 128x4B per half-block)
    if (t < 128)
      rowpart[(size_t)cx * N + by * 128 + t] = sm[t];
    else
      colpart[(size_t)by * N + cx * 128 + (t - 128)] = sm[t];

  } else if (bid < 4352) {
    const int sb = bid - 4096;                 // 0..255, 256 pairs each
    const int grp = lane >> 3, sub = lane & 7;
    float exacc = 0.f, msacc = 0.f;
    #pragma unroll 2
    for (int pass = 0; pass < 8; ++pass) {
      const int p = sb * 256 + pass * 32 + wid * 8 + grp;   // pair id
      int u = u_idx[p], i = i_idx[p];
      short8v uv = *reinterpret_cast<const short8v*>(Ub + (size_t)u * D + sub * 8);
      short8v iv = *reinterpret_cast<const short8v*>(Rb + (size_t)i * D + sub * 8);
      float pd = 0.f;
      #pragma unroll
      for (int e = 0; e < 8; ++e)
        pd += bf16_to_f32((unsigned short)uv[e]) * bf16_to_f32((unsigned short)iv[e]);
      pd += __shfl_xor(pd, 1, 64);
      pd += __shfl_xor(pd, 2, 64);
      pd += __shfl_xor(pd, 4, 64);             // dot complete in all 8 lanes
      if (sub == 0) {
        float rv = ratings[p];
        exacc += (rv - FILL) * pd;             // scaled by log2e; fixed later
        float dd = rv - cossim[p];
        msacc += dd * dd;
        atomicAdd(&rowRMe[u], rv - FILL);      // spread over 8192 addresses
      }
    }
    exacc += __shfl_xor(exacc, 8, 64);
    exacc += __shfl_xor(exacc, 16, 64);
    exacc += __shfl_xor(exacc, 32, 64);
    msacc += __shfl_xor(msacc, 8, 64);
    msacc += __shfl_xor(msacc, 16, 64);
    msacc += __shfl_xor(msacc, 32, 64);
    if (lane == 0) { sm[wid] = exacc; sm[8 + wid] = msacc; }
    __syncthreads();
    if (t == 0)
      atomicAdd(&scal[1], (double)(sm[0] + sm[1] + sm[2] + sm[3]));
    else if (t == 64)
      atomicAdd(&scal[2], (double)(sm[8] + sm[9] + sm[10] + sm[11]));

  } else {
    // column sums. lane l reads row (base + l>>3), cols (l&7)*8..+7 as one
    // short8v; 8 passes of 32 rows per block.
    int sb = bid - 4352;                   // 0..63
    const short* M = (sb < 32) ? Ub : Rb;
    float* dst = (sb < 32) ? sumU : sumR;
    int rbase = (sb & 31) * 256;
    float pc[8] = {};
    #pragma unroll
    for (int p = 0; p < 8; ++p) {
      int row = rbase + p * 32 + wid * 8 + (lane >> 3);
      short8v v = *reinterpret_cast<const short8v*>(M + (size_t)row * D + (lane & 7) * 8);
      #pragma unroll
      for (int e = 0; e < 8; ++e)
        pc[e] += bf16_to_f32((unsigned short)v[e]);
    }
    #pragma unroll
    for (int e = 0; e < 8; ++e) {
      pc[e] += __shfl_xor(pc[e], 8, 64);
      pc[e] += __shfl_xor(pc[e], 16, 64);
      pc[e] += __shfl_xor(pc[e], 32, 64);
    }
    if (lane < 8)
      #pragma unroll
      for (int e = 0; e < 8; ++e) sm[wid * 64 + lane * 8 + e] = pc[e];
    __syncthreads();
    if (t < 64)
      atomicAdd(&dst[t], sm[t] + sm[64 + t] + sm[128 + t] + sm[192 + t]);
  }
}

// 128 blocks x 64 rows; 4 thread-quarters per row reduce 16 row-slices +
// 16 col-slices each, LDS-combine, log term -> scal[3]. Last block
// (completion counter in scal[7]) computes the final scalar output.
__global__ __launch_bounds__(256) void final_out_kernel(
    const float* __restrict__ rowpart, const float* __restrict__ colpart,
    const float* __restrict__ rowRMe, const float* __restrict__ sumU,
    const float* __restrict__ sumR, double* __restrict__ scal,
    float* __restrict__ out) {
  __shared__ float smr[256];
  __shared__ float smc[256];
  __shared__ unsigned int done;
  const int t = threadIdx.x;
  const int q = t >> 6, r = t & 63;          // quarter, row-in-block
  const int i = blockIdx.x * 64 + r;
  float rsum = 0.f, csum = 0.f;
  #pragma unroll 8
  for (int p = q * 16; p < q * 16 + 16; ++p) {
    rsum += rowpart[(size_t)p * N + i];
    csum += colpart[(size_t)p * N + i];
  }
  smr[t] = rsum; smc[t] = csum;
  __syncthreads();
  if (t < 64) {
    rsum = smr[t] + smr[64 + t] + smr[128 + t] + smr[192 + t];
    csum = smc[t] + smc[64 + t] + smc[128 + t] + smc[192 + t];
    float term = (FILL * (float)N + rowRMe[i]) * 0.5f * (logf(rsum) + logf(csum));
    float s = wave_reduce_sum(term);
    if (t == 0) {
      atomicAdd(&scal[3], (double)s);
      __threadfence();
    }
  }
  __syncthreads();
  unsigned int* cnt = (unsigned int*)(scal + 7);
  if (t == 0) {
    __threadfence();
    done = atomicAdd(cnt, 1u);
  }
  __syncthreads();
  if (done == 127 && t < 64) {               // last of 128 blocks finishes up
    __threadfence();
    float p = sumU[t] * sumR[t];
    p = wave_reduce_sum(p);                  // = log2e * sum(cos)
    if (t == 0) {
      double T = (0.1 * (double)p + scal[1]) * LN2;   // undo log2e scaling
      double contrastive = (scal[3] - T) / (double)N;
      double mse = scal[2] / (double)B_PAIRS;
      out[0] = (float)(0.5 * contrastive + 0.5 * mse);
      *cnt = 0u;                             // leave counter clean for replay
    }
  }
}

extern "C" void kernel_launch(void* const* d_in, const int* in_sizes, int n_in,
                              void* d_out, int out_size, void* d_ws, size_t ws_size,
                              hipStream_t stream) {
  const float* U       = (const float*)d_in[0];
  const float* R       = (const float*)d_in[1];
  const float* ratings = (const float*)d_in[2];
  const float* cossim  = (const float*)d_in[3];
  const int*   u_idx   = (const int*)d_in[4];
  const int*   i_idx   = (const int*)d_in[5];

  float* ws      = (float*)d_ws;
  float* rowRMe  = ws;                      // [8192]
  float* sumU    = ws + 8192;               // [64]
  float* sumR    = ws + 8256;               // [64]
  double* scal   = (double*)(ws + 8320);    // 8 doubles; [7] = completion counter
  short* Ub      = (short*)(ws + 8448);     // [N*D] bf16 (scaled by log2e)
  short* Rb      = Ub + (size_t)N * D;      // [N*D] bf16
  float* rowpart = ws + 532736;             // [64][8192] slice per col-tile cx
  float* colpart = ws + 1057024;            // [64][8192] slice per row-tile by
  // total ws use: 1581312 floats ≈ 6.3 MB

  norm_kernel<<<(2 * N) / 4, 256, 0, stream>>>(U, R, Ub, Rb, rowRMe, sumU, sumR, scal);

  mega_kernel<<<4416, 256, 0, stream>>>(Ub, Rb, ratings, cossim, u_idx, i_idx,
                                        rowRMe, sumU, sumR, scal, rowpart, colpart);

  final_out_kernel<<<128, 256, 0, stream>>>(rowpart, colpart, rowRMe,
                                            sumU, sumR, scal, (float*)d_out);
}

// Round 18
// 58.893 us; speedup vs baseline: 1.9718x; 1.0605x over previous
//
#include <hip/hip_runtime.h>
#include <hip/hip_bf16.h>

#define N 8192        // n_users == n_recipes (required by reference broadcasting)
#define D 64
#define B_PAIRS 65536
#define FILL 0.1f
#define LOG2E 1.4426950408889634f
#define LN2 0.6931471805599453

typedef __attribute__((ext_vector_type(8))) short short8v;   // 8 bf16 in 4 VGPRs
typedef __attribute__((ext_vector_type(4))) float f32x4;

__device__ __forceinline__ float wave_reduce_sum(float v) {
  #pragma unroll
  for (int m = 1; m < 64; m <<= 1) v += __shfl_xor(v, m, 64);
  return v;
}

__device__ __forceinline__ float bf16_to_f32(unsigned short u) {
  unsigned int b = ((unsigned int)u) << 16;
  return __builtin_bit_cast(float, b);
}

__device__ __forceinline__ short f32_bf16_rne(float f) {
  unsigned int b = __builtin_bit_cast(unsigned int, f);
  return (short)((b + 0x7FFFu + ((b >> 16) & 1u)) >> 16);
}

// v_exp_f32 via builtin (compiler handles the trans-op wait states; raw asm
// without s_nop corrupted results in R8). Args bounded: |x| <= ~1.45.
__device__ __forceinline__ float fast_exp2(float x) {
#if __has_builtin(__builtin_amdgcn_exp2f)
  return __builtin_amdgcn_exp2f(x);
#else
  float r;
  asm("v_exp_f32 %0, %1\n\ts_nop 1" : "=v"(r) : "v"(x));
  return r;
#endif
}

// Vectorized norm: 16 threads/row, float4 loads (16B/lane), short4 stores.
// L2-normalize, emit bf16 (RNE); U side pre-scaled by log2(e) so the gemm
// uses raw exp2 (corrected by *ln2 on cos-sum terms). Side duty: zero-init
// accumulators + completion counter (graph-replay-safe).
__global__ __launch_bounds__(256) void norm_kernel(const float* __restrict__ U,
                                                   const float* __restrict__ R,
                                                   short* __restrict__ Ub,
                                                   short* __restrict__ Rb,
                                                   float* __restrict__ rowRMe,
                                                   float* __restrict__ sumU,
                                                   float* __restrict__ sumR,
                                                   double* __restrict__ scal) {
  const int t = threadIdx.x;
  const int b = blockIdx.x;
  if (b < 32) {
    rowRMe[b * 256 + t] = 0.f;
  } else if (b == 32) {
    if (t < 64) sumU[t] = 0.f;
    else if (t < 128) sumR[t - 64] = 0.f;
    else if (t < 136) scal[t - 128] = 0.0;   // scal[0..7]; [7] doubles as counter
  }
  int row = b * 16 + (t >> 4);               // 16 rows/block
  int c = t & 15;                            // float4 index within row
  bool isU = row < N;
  const float* src = isU ? (U + (size_t)row * D) : (R + (size_t)(row - N) * D);
  float4 v = reinterpret_cast<const float4*>(src)[c];
  float ss = v.x * v.x + v.y * v.y + v.z * v.z + v.w * v.w;
  ss += __shfl_xor(ss, 1, 64);
  ss += __shfl_xor(ss, 2, 64);
  ss += __shfl_xor(ss, 4, 64);
  ss += __shfl_xor(ss, 8, 64);               // row sum-sq in its 16-lane group
  float scale = rsqrtf(ss) * (isU ? LOG2E : 1.0f);   // norms ~8; eps never binds
  short4 o;
  o.x = f32_bf16_rne(v.x * scale);
  o.y = f32_bf16_rne(v.y * scale);
  o.z = f32_bf16_rne(v.z * scale);
  o.w = f32_bf16_rne(v.w * scale);
  short* dst = isU ? (Ub + (size_t)row * D) : (Rb + (size_t)(row - N) * D);
  reinterpret_cast<short4*>(dst)[c] = o;
}

// Fused kernel — AUX SECTIONS FIRST so their latency-bound blocks start at
// t=0 and overlap under the gemm instead of trailing it (R17: 320 aux blocks
// dispatched last = ~8us straggler tail on top of R9's 39.6us gemm).
// blocks 0..255:    scattered interactions (R11-verified): 8 lanes/pair,
//                   256 pairs/block, per-block combine -> ONE double atomic
//                   per scalar/block. Dedup ignored (~32 collisions, ~1e-3).
// blocks 256..319:  column sums of Ub/Rb for S_cos (R11-verified).
// blocks 320..4415: R9's gemm (best section measured: 39.6us): 128x128 block,
//                   4 waves 2x2, straight-line 16 fragment loads after the
//                   init-barrier, fused exp + reductions, LDS combine,
//                   COALESCED partial stores.
__global__ __launch_bounds__(256, 4) void mega_kernel(
    const short* __restrict__ Ub, const short* __restrict__ Rb,
    const float* __restrict__ ratings, const float* __restrict__ cossim,
    const int* __restrict__ u_idx, const int* __restrict__ i_idx,
    float* __restrict__ rowRMe, float* __restrict__ sumU,
    float* __restrict__ sumR, double* __restrict__ scal,
    float* __restrict__ rowpart, float* __restrict__ colpart) {
  __shared__ float sm[256];      // gemm: [0..127]=rs, [128..255]=cs
  const int bid = blockIdx.x;
  const int t = threadIdx.x;
  const int wid = t >> 6, lane = t & 63;

  if (bid >= 320) {
    const int g = bid - 320;
    const int cx = g & 63, by = g >> 6;
    const int wr = wid >> 1, wc = wid & 1;
    const int rowbase = by * 128 + wr * 64;
    const int colbase = cx * 128 + wc * 64;
    const int lrow = lane & 15;   // fragment row (A) / col (B) index
    const int kgrp = lane >> 4;   // k-group: k = ks*32 + kgrp*8 + j

    sm[t] = 0.f;
    __syncthreads();             // BEFORE loads: barrier drain can't stall prefetch

    short8v aF[4][2], bF[4][2];
    #pragma unroll
    for (int m = 0; m < 4; ++m) {
      const short* arow = Ub + (size_t)(rowbase + m * 16 + lrow) * D + kgrp * 8;
      aF[m][0] = *reinterpret_cast<const short8v*>(arow);
      aF[m][1] = *reinterpret_cast<const short8v*>(arow + 32);
    }
    #pragma unroll
    for (int n = 0; n < 4; ++n) {
      const short* brow = Rb + (size_t)(colbase + n * 16 + lrow) * D + kgrp * 8;
      bF[n][0] = *reinterpret_cast<const short8v*>(brow);
      bF[n][1] = *reinterpret_cast<const short8v*>(brow + 32);
    }

    float rowacc[4][4] = {};   // [m][reg]
    #pragma unroll
    for (int n = 0; n < 4; ++n) {
      f32x4 acc[4] = {};
      #pragma unroll
      for (int m = 0; m < 4; ++m)
        acc[m] = __builtin_amdgcn_mfma_f32_16x16x32_bf16(aF[m][0], bF[n][0], acc[m], 0, 0, 0);
      #pragma unroll
      for (int m = 0; m < 4; ++m)
        acc[m] = __builtin_amdgcn_mfma_f32_16x16x32_bf16(aF[m][1], bF[n][1], acc[m], 0, 0, 0);
      float p0 = 0.f, p1 = 0.f, p2 = 0.f, p3 = 0.f;
      #pragma unroll
      for (int r = 0; r < 4; ++r) {
        float e0 = fast_exp2(acc[0][r]); rowacc[0][r] += e0; p0 += e0;
        float e1 = fast_exp2(acc[1][r]); rowacc[1][r] += e1; p1 += e1;
        float e2 = fast_exp2(acc[2][r]); rowacc[2][r] += e2; p2 += e2;
        float e3 = fast_exp2(acc[3][r]); rowacc[3][r] += e3; p3 += e3;
      }
      float cacc = (p0 + p1) + (p2 + p3);
      cacc += __shfl_xor(cacc, 16, 64);
      cacc += __shfl_xor(cacc, 32, 64);
      if (lane < 16) atomicAdd(&sm[128 + wc * 64 + n * 16 + lrow], cacc);  // LDS
    }

    // row epilogue: reduce over lrow; writer lanes cover 16 rows via kgrp,reg
    #pragma unroll
    for (int m = 0; m < 4; ++m)
      #pragma unroll
      for (int r = 0; r < 4; ++r) {
        float v = rowacc[m][r];
        v += __shfl_xor(v, 1, 64);
        v += __shfl_xor(v, 2, 64);
        v += __shfl_xor(v, 4, 64);
        v += __shfl_xor(v, 8, 64);
        if (lrow == 0)
          atomicAdd(&sm[wr * 64 + m * 16 + kgrp * 4 + r], v);             // LDS
      }
    __syncthreads();

    // coalesced partial stores (contiguous 128x4B per half-block)
    if (t < 128)
      rowpart[(size_t)cx * N + by * 128 + t] = sm[t];
    else
      colpart[(size_t)by * N + cx * 128 + (t - 128)] = sm[t];

  } else if (bid < 256) {
    const int sb = bid;                        // 0..255, 256 pairs each
    const int grp = lane >> 3, sub = lane & 7;
    float exacc = 0.f, msacc = 0.f;
    #pragma unroll 2
    for (int pass = 0; pass < 8; ++pass) {
      const int p = sb * 256 + pass * 32 + wid * 8 + grp;   // pair id
      int u = u_idx[p], i = i_idx[p];
      short8v uv = *reinterpret_cast<const short8v*>(Ub + (size_t)u * D + sub * 8);
      short8v iv = *reinterpret_cast<const short8v*>(Rb + (size_t)i * D + sub * 8);
      float pd = 0.f;
      #pragma unroll
      for (int e = 0; e < 8; ++e)
        pd += bf16_to_f32((unsigned short)uv[e]) * bf16_to_f32((unsigned short)iv[e]);
      pd += __shfl_xor(pd, 1, 64);
      pd += __shfl_xor(pd, 2, 64);
      pd += __shfl_xor(pd, 4, 64);             // dot complete in all 8 lanes
      if (sub == 0) {
        float rv = ratings[p];
        exacc += (rv - FILL) * pd;             // scaled by log2e; fixed later
        float dd = rv - cossim[p];
        msacc += dd * dd;
        atomicAdd(&rowRMe[u], rv - FILL);      // spread over 8192 addresses
      }
    }
    exacc += __shfl_xor(exacc, 8, 64);
    exacc += __shfl_xor(exacc, 16, 64);
    exacc += __shfl_xor(exacc, 32, 64);
    msacc += __shfl_xor(msacc, 8, 64);
    msacc += __shfl_xor(msacc, 16, 64);
    msacc += __shfl_xor(msacc, 32, 64);
    if (lane == 0) { sm[wid] = exacc; sm[8 + wid] = msacc; }
    __syncthreads();
    if (t == 0)
      atomicAdd(&scal[1], (double)(sm[0] + sm[1] + sm[2] + sm[3]));
    else if (t == 64)
      atomicAdd(&scal[2], (double)(sm[8] + sm[9] + sm[10] + sm[11]));

  } else {
    // column sums. lane l reads row (base + l>>3), cols (l&7)*8..+7 as one
    // short8v; 8 passes of 32 rows per block.
    int sb = bid - 256;                    // 0..63
    const short* M = (sb < 32) ? Ub : Rb;
    float* dst = (sb < 32) ? sumU : sumR;
    int rbase = (sb & 31) * 256;
    float pc[8] = {};
    #pragma unroll
    for (int p = 0; p < 8; ++p) {
      int row = rbase + p * 32 + wid * 8 + (lane >> 3);
      short8v v = *reinterpret_cast<const short8v*>(M + (size_t)row * D + (lane & 7) * 8);
      #pragma unroll
      for (int e = 0; e < 8; ++e)
        pc[e] += bf16_to_f32((unsigned short)v[e]);
    }
    #pragma unroll
    for (int e = 0; e < 8; ++e) {
      pc[e] += __shfl_xor(pc[e], 8, 64);
      pc[e] += __shfl_xor(pc[e], 16, 64);
      pc[e] += __shfl_xor(pc[e], 32, 64);
    }
    if (lane < 8)
      #pragma unroll
      for (int e = 0; e < 8; ++e) sm[wid * 64 + lane * 8 + e] = pc[e];
    __syncthreads();
    if (t < 64)
      atomicAdd(&dst[t], sm[t] + sm[64 + t] + sm[128 + t] + sm[192 + t]);
  }
}

// 128 blocks x 64 rows; 4 thread-quarters per row reduce 16 row-slices +
// 16 col-slices each, LDS-combine, log term -> scal[3]. Last block
// (completion counter in scal[7]) computes the final scalar output.
__global__ __launch_bounds__(256) void final_out_kernel(
    const float* __restrict__ rowpart, const float* __restrict__ colpart,
    const float* __restrict__ rowRMe, const float* __restrict__ sumU,
    const float* __restrict__ sumR, double* __restrict__ scal,
    float* __restrict__ out) {
  __shared__ float smr[256];
  __shared__ float smc[256];
  __shared__ unsigned int done;
  const int t = threadIdx.x;
  const int q = t >> 6, r = t & 63;          // quarter, row-in-block
  const int i = blockIdx.x * 64 + r;
  float rsum = 0.f, csum = 0.f;
  #pragma unroll 8
  for (int p = q * 16; p < q * 16 + 16; ++p) {
    rsum += rowpart[(size_t)p * N + i];
    csum += colpart[(size_t)p * N + i];
  }
  smr[t] = rsum; smc[t] = csum;
  __syncthreads();
  if (t < 64) {
    rsum = smr[t] + smr[64 + t] + smr[128 + t] + smr[192 + t];
    csum = smc[t] + smc[64 + t] + smc[128 + t] + smc[192 + t];
    float term = (FILL * (float)N + rowRMe[i]) * 0.5f * (logf(rsum) + logf(csum));
    float s = wave_reduce_sum(term);
    if (t == 0) {
      atomicAdd(&scal[3], (double)s);
      __threadfence();
    }
  }
  __syncthreads();
  unsigned int* cnt = (unsigned int*)(scal + 7);
  if (t == 0) {
    __threadfence();
    done = atomicAdd(cnt, 1u);
  }
  __syncthreads();
  if (done == 127 && t < 64) {               // last of 128 blocks finishes up
    __threadfence();
    float p = sumU[t] * sumR[t];
    p = wave_reduce_sum(p);                  // = log2e * sum(cos)
    if (t == 0) {
      double T = (0.1 * (double)p + scal[1]) * LN2;   // undo log2e scaling
      double contrastive = (scal[3] - T) / (double)N;
      double mse = scal[2] / (double)B_PAIRS;
      out[0] = (float)(0.5 * contrastive + 0.5 * mse);
      *cnt = 0u;                             // leave counter clean for replay
    }
  }
}

extern "C" void kernel_launch(void* const* d_in, const int* in_sizes, int n_in,
                              void* d_out, int out_size, void* d_ws, size_t ws_size,
                              hipStream_t stream) {
  const float* U       = (const float*)d_in[0];
  const float* R       = (const float*)d_in[1];
  const float* ratings = (const float*)d_in[2];
  const float* cossim  = (const float*)d_in[3];
  const int*   u_idx   = (const int*)d_in[4];
  const int*   i_idx   = (const int*)d_in[5];

  float* ws      = (float*)d_ws;
  float* rowRMe  = ws;                      // [8192]
  float* sumU    = ws + 8192;               // [64]
  float* sumR    = ws + 8256;               // [64]
  double* scal   = (double*)(ws + 8320);    // 8 doubles; [7] = completion counter
  short* Ub      = (short*)(ws + 8448);     // [N*D] bf16 (scaled by log2e)
  short* Rb      = Ub + (size_t)N * D;      // [N*D] bf16
  float* rowpart = ws + 532736;             // [64][8192] slice per col-tile cx
  float* colpart = ws + 1057024;            // [64][8192] slice per row-tile by
  // total ws use: 1581312 floats ≈ 6.3 MB

  norm_kernel<<<(2 * N) / 16, 256, 0, stream>>>(U, R, Ub, Rb, rowRMe, sumU, sumR, scal);

  mega_kernel<<<4416, 256, 0, stream>>>(Ub, Rb, ratings, cossim, u_idx, i_idx,
                                        rowRMe, sumU, sumR, scal, rowpart, colpart);

  final_out_kernel<<<128, 256, 0, stream>>>(rowpart, colpart, rowRMe,
                                            sumU, sumR, scal, (float*)d_out);
}